// Round 4
// baseline (254.529 us; speedup 1.0000x reference)
//
#include <hip/hip_runtime.h>

// Problem constants: B=8, L=64, D=768, H=12, d=64
#define DMODEL 768
#define NHEADS 12
#define RTOT   512           // B*L rows
#define BIW    9216          // NHEADS*DMODEL (per-(b,i) u/w row)

// ---------------------------------------------------------------------------
// 16x32-tile fp32 GEMM, register-double-buffered K chunks of 64.
// dst[r, ct*32+c] = (sum_k src[r*ars + sk + k]*W[k, ct*32+c] + bias)*scale
// grid = (32, 24), 256 threads
// ---------------------------------------------------------------------------
__global__ __launch_bounds__(256) void linear16(
    const float* __restrict__ src, int ars, int scm,
    const float* __restrict__ W, const float* __restrict__ bias,
    float* __restrict__ dst, int drs, float scale)
{
    __shared__ float At[16][64];   // 4 KB
    __shared__ float Bt[64][32];   // 8 KB
    const int rt = blockIdx.x, ct = blockIdx.y, t = threadIdx.x;
    const int sk = ((ct * 32) >> 6) * scm;
    const int c  = t & 31;
    const int rg = t >> 5;             // 8 groups x 2 rows

    const int ar0 = t >> 4,          ak0 = t & 15;          // 1 float4 A
    const int bk0 = t >> 3,          bc0 = (t & 7) * 4;     // 2 float4 B
    const int bk1 = (t + 256) >> 3,  bc1 = ((t + 256) & 7) * 4;

    float4 va0, vb0, vb1;
    auto LD = [&](int kb) {
        va0 = *(const float4*)&src[(size_t)(rt * 16 + ar0) * ars + sk + kb * 64 + ak0 * 4];
        vb0 = *(const float4*)&W[(size_t)(kb * 64 + bk0) * DMODEL + ct * 32 + bc0];
        vb1 = *(const float4*)&W[(size_t)(kb * 64 + bk1) * DMODEL + ct * 32 + bc1];
    };

    LD(0);
    float acc[2] = {0.f, 0.f};

    for (int kb = 0; kb < 12; ++kb) {
        if (kb) __syncthreads();
        *(float4*)&At[ar0][ak0 * 4] = va0;
        *(float4*)&Bt[bk0][bc0] = vb0;
        *(float4*)&Bt[bk1][bc1] = vb1;
        __syncthreads();
        if (kb < 11) LD(kb + 1);
        #pragma unroll
        for (int kq = 0; kq < 16; ++kq) {
            float b0 = Bt[kq * 4 + 0][c], b1 = Bt[kq * 4 + 1][c];
            float b2 = Bt[kq * 4 + 2][c], b3 = Bt[kq * 4 + 3][c];
            #pragma unroll
            for (int i = 0; i < 2; ++i) {
                float4 a = *(const float4*)&At[rg * 2 + i][kq * 4];
                acc[i] += a.x * b0 + a.y * b1 + a.z * b2 + a.w * b3;
            }
        }
    }
    const float bb = bias[ct * 32 + c];
    #pragma unroll
    for (int i = 0; i < 2; ++i)
        dst[(size_t)(rt * 16 + rg * 2 + i) * drs + ct * 32 + c] = (acc[i] + bb) * scale;
}

// ---------------------------------------------------------------------------
// u[r, h, m] = sum_d Qp[r, h*64+d] * Wk[m, h*64+d];  cvec[r,h] = sum_d bk[h*64+d]*Qp[r,h*64+d]
// grid = (16, 12, 12), 256 threads
// ---------------------------------------------------------------------------
__global__ __launch_bounds__(256) void u_kernel(
    const float* __restrict__ qp, const float* __restrict__ Wk, const float* __restrict__ bk,
    float* __restrict__ u, float* __restrict__ cvec)
{
    __shared__ float Qt[32][64];    // 8 KB
    __shared__ float Bt[64][65];    // 16.25 KB (pad -> conflict-free b32 row reads)
    const int rt = blockIdx.x, mt = blockIdx.y, h = blockIdx.z, t = threadIdx.x;

    #pragma unroll
    for (int kk = 0; kk < 2; ++kk) {
        int i4 = t + kk * 256;
        int r = i4 >> 4, dq = i4 & 15;
        *(float4*)&Qt[r][dq * 4] =
            *(const float4*)&qp[(size_t)(rt * 32 + r) * DMODEL + h * 64 + dq * 4];
    }
    #pragma unroll
    for (int kk = 0; kk < 4; ++kk) {
        int i4 = t + kk * 256;
        int m = i4 >> 4, dq = i4 & 15;
        float4 v = *(const float4*)&Wk[(size_t)(mt * 64 + m) * DMODEL + h * 64 + dq * 4];
        Bt[m][dq * 4 + 0] = v.x; Bt[m][dq * 4 + 1] = v.y;
        Bt[m][dq * 4 + 2] = v.z; Bt[m][dq * 4 + 3] = v.w;
    }
    __syncthreads();

    const int c = t & 63, rg = t >> 6;
    float acc[8] = {0.f,0.f,0.f,0.f,0.f,0.f,0.f,0.f};
    #pragma unroll
    for (int dq = 0; dq < 16; ++dq) {
        float b0 = Bt[c][dq * 4 + 0], b1 = Bt[c][dq * 4 + 1];
        float b2 = Bt[c][dq * 4 + 2], b3 = Bt[c][dq * 4 + 3];
        #pragma unroll
        for (int i = 0; i < 8; ++i) {
            float4 a = *(const float4*)&Qt[rg * 8 + i][dq * 4];
            acc[i] += a.x * b0 + a.y * b1 + a.z * b2 + a.w * b3;
        }
    }
    #pragma unroll
    for (int i = 0; i < 8; ++i)
        u[(size_t)(rt * 32 + rg * 8 + i) * BIW + h * DMODEL + mt * 64 + c] = acc[i];

    if (mt == 0 && t < 32) {
        float s = 0.f;
        for (int d = 0; d < 64; ++d) s += bk[h * 64 + d] * Qt[t][d];
        cvec[(rt * 32 + t) * NHEADS + h] = s;
    }
}

// ---------------------------------------------------------------------------
// Core: per (b,i) block, 512 threads (8 waves).
// Phase 1: coalesced key stream (m across lanes), u in LDS, 30-shfl split-tree.
// Softmax per head per wave.
// Phase 3: j-SPLIT halves (value read exactly once), partial-w reduce via u_sh.
// ---------------------------------------------------------------------------
__global__ __launch_bounds__(512, 4) void attn_core(
    const float* __restrict__ key, const float* __restrict__ value, const float* __restrict__ mask,
    const float* __restrict__ u, const float* __restrict__ cvec, float* __restrict__ w)
{
    __shared__ float u_sh[NHEADS * DMODEL];   // 36 KB (u in phase 1; w-partials in phase 3)
    __shared__ float sc[NHEADS][66];          // scores -> attn in place

    const int bi   = blockIdx.x;
    const int t    = threadIdx.x;
    const int lane = t & 63;
    const int wv   = t >> 6;                  // wave 0..7
    const size_t kvb = (size_t)bi * 64 * DMODEL;

    // stage u[bi] (36 KB), coalesced
    #pragma unroll
    for (int kk = 0; kk < 5; ++kk) {
        int idx = (t + kk * 512) * 4;
        if (idx < NHEADS * DMODEL)
            *(float4*)&u_sh[idx] = *(const float4*)&u[(size_t)bi * BIW + idx];
    }
    __syncthreads();

    // ---- phase 1: wave wv owns rows j = wv*8 .. wv*8+7, 4 rows per sub-iter
    #pragma unroll
    for (int rb = 0; rb < 2; ++rb) {
        const int j0 = wv * 8 + rb * 4;
        // issue ALL 12 key loads for this 4-row batch up front
        float4 k4[3][4];
        #pragma unroll
        for (int cch = 0; cch < 3; ++cch)
            #pragma unroll
            for (int r = 0; r < 4; ++r)
                k4[cch][r] = *(const float4*)&key[kvb + (size_t)(j0 + r) * DMODEL + cch * 256 + lane * 4];

        float a[NHEADS][4];
        #pragma unroll
        for (int h = 0; h < NHEADS; ++h)
            #pragma unroll
            for (int r = 0; r < 4; ++r) a[h][r] = 0.f;

        #pragma unroll
        for (int cch = 0; cch < 3; ++cch)
            #pragma unroll
            for (int h = 0; h < NHEADS; ++h) {
                float4 u4 = *(const float4*)&u_sh[h * DMODEL + cch * 256 + lane * 4];
                #pragma unroll
                for (int r = 0; r < 4; ++r)
                    a[h][r] += k4[cch][r].x * u4.x + k4[cch][r].y * u4.y + k4[cch][r].z * u4.z + k4[cch][r].w * u4.w;
            }

        // split-tree reduce: 12 heads over 64 lanes -> 30 shfl per row
        #pragma unroll
        for (int r = 0; r < 4; ++r) {
            float s6[6];
            #pragma unroll
            for (int i = 0; i < 6; ++i) {
                float lo = a[i][r], hi = a[i + 6][r];
                float tl = __shfl_xor(lo, 32), th = __shfl_xor(hi, 32);
                s6[i] = (lane < 32) ? lo + tl : hi + th;
            }
            float s3[3];
            #pragma unroll
            for (int i = 0; i < 3; ++i) {
                float lo = s6[i], hi = s6[i + 3];
                float tl = __shfl_xor(lo, 16), th = __shfl_xor(hi, 16);
                s3[i] = ((lane & 16) == 0) ? lo + tl : hi + th;
            }
            #pragma unroll
            for (int o = 8; o >= 1; o >>= 1)
                #pragma unroll
                for (int i = 0; i < 3; ++i) s3[i] += __shfl_xor(s3[i], o);
            if ((lane & 15) == 0) {
                const int g = lane >> 4;
                #pragma unroll
                for (int i = 0; i < 3; ++i) sc[g * 3 + i][j0 + r] = s3[i];
            }
        }
    }
    __syncthreads();

    // ---- softmax: wave wv -> head wv; waves 0..3 also head 8+wv
    {
        const float mk = mask[bi * 64 + lane];
        #pragma unroll
        for (int hh = 0; hh < 2; ++hh) {
            const int h = wv + hh * 8;
            if (h < NHEADS) {
                float s = (sc[h][lane] + cvec[bi * NHEADS + h]) * mk;
                float mx = s;
                #pragma unroll
                for (int o = 1; o < 64; o <<= 1) mx = fmaxf(mx, __shfl_xor(mx, o));
                float e = __expf(s - mx);
                float sm = e;
                #pragma unroll
                for (int o = 1; o < 64; o <<= 1) sm += __shfl_xor(sm, o);
                sc[h][lane] = e / sm;
            }
        }
    }
    __syncthreads();

    // ---- phase 3: j-split halves. half hb: j in [hb*32, hb*32+32), ALL 12 heads,
    //      m = mo + {0,256,512}. value read exactly once per block.
    {
        const int hb = t >> 8, mo = t & 255;
        const int jbeg = hb * 32;
        float a3[NHEADS][3];
        #pragma unroll
        for (int h = 0; h < NHEADS; ++h) { a3[h][0] = 0.f; a3[h][1] = 0.f; a3[h][2] = 0.f; }
        const float* vb = value + kvb + mo;
        #pragma unroll 4
        for (int jj = 0; jj < 32; ++jj) {
            const int j = jbeg + jj;
            float v0 = vb[(size_t)j * DMODEL];
            float v1 = vb[(size_t)j * DMODEL + 256];
            float v2 = vb[(size_t)j * DMODEL + 512];
            #pragma unroll
            for (int h = 0; h < NHEADS; ++h) {
                float av = sc[h][j];
                a3[h][0] += av * v0;
                a3[h][1] += av * v1;
                a3[h][2] += av * v2;
            }
        }
        // reduce the two j-halves through u_sh (free after phase 1)
        if (hb == 0) {
            #pragma unroll
            for (int h = 0; h < NHEADS; ++h)
                #pragma unroll
                for (int mm = 0; mm < 3; ++mm)
                    u_sh[h * DMODEL + mo + mm * 256] = a3[h][mm];
        }
        __syncthreads();
        if (hb == 1) {
            #pragma unroll
            for (int h = 0; h < NHEADS; ++h)
                #pragma unroll
                for (int mm = 0; mm < 3; ++mm)
                    w[(size_t)bi * BIW + h * DMODEL + mo + mm * 256] =
                        a3[h][mm] + u_sh[h * DMODEL + mo + mm * 256];
        }
    }
}

// ---------------------------------------------------------------------------
extern "C" void kernel_launch(void* const* d_in, const int* in_sizes, int n_in,
                              void* d_out, int out_size, void* d_ws, size_t ws_size,
                              hipStream_t stream) {
    const float* key   = (const float*)d_in[0];
    const float* value = (const float*)d_in[1];
    const float* query = (const float*)d_in[2];
    const float* mask  = (const float*)d_in[3];
    const float* Wk    = (const float*)d_in[4];
    const float* bk    = (const float*)d_in[5];
    const float* Wv    = (const float*)d_in[6];
    const float* bv    = (const float*)d_in[7];
    const float* Wq    = (const float*)d_in[8];
    const float* bq    = (const float*)d_in[9];
    const float* Wo    = (const float*)d_in[10];
    const float* bo    = (const float*)d_in[11];
    float* out = (float*)d_out;

    float* wsf    = (float*)d_ws;
    float* qp_ctx = wsf;                                // 512*768 (Qp, later ctx)
    float* u_w    = wsf + (size_t)RTOT * DMODEL;        // 512*9216 (u, later w)
    float* cvec   = u_w + (size_t)RTOT * BIW;           // 512*12

    // 1. Qp = (query @ Wq + bq) / 8
    linear16<<<dim3(32, 24), 256, 0, stream>>>(query, DMODEL, 0, Wq, bq, qp_ctx, DMODEL, 0.125f);
    // 2. u[r,h,m], cvec[r,h]
    u_kernel<<<dim3(16, 12, 12), 256, 0, stream>>>(qp_ctx, Wk, bk, u_w, cvec);
    // 3. scores/softmax/w  (w overwrites u region; u staged to LDS before w writes)
    attn_core<<<512, 512, 0, stream>>>(key, value, mask, u_w, cvec, u_w);
    // 4. ctx[r, h*64+cc] = w[r,h,:] @ Wv[:, h*64+cc] + bv
    linear16<<<dim3(32, 24), 256, 0, stream>>>(u_w, BIW, DMODEL, Wv, bv, qp_ctx, DMODEL, 1.0f);
    // 5. out = ctx @ Wo + bo
    linear16<<<dim3(32, 24), 256, 0, stream>>>(qp_ctx, DMODEL, 0, Wo, bo, out, DMODEL, 1.0f);
}

// Round 5
// 154.342 us; speedup vs baseline: 1.6491x; 1.6491x over previous
//
#include <hip/hip_runtime.h>

// Problem constants: B=8, L=64, D=768, H=12, d=64
#define DMODEL 768
#define NHEADS 12
#define RTOT   512           // B*L rows
#define BIW    9216          // NHEADS*DMODEL (per-(b,i) u/w row)

// ---------------------------------------------------------------------------
// 16x32-tile fp32 GEMM, register-double-buffered K chunks of 64.
// dst[r, ct*32+c] = (sum_k src[r*ars + sk + k]*W[k, ct*32+c] + bias)*scale
// grid = (32, 24), 256 threads
// ---------------------------------------------------------------------------
__global__ __launch_bounds__(256) void linear16(
    const float* __restrict__ src, int ars, int scm,
    const float* __restrict__ W, const float* __restrict__ bias,
    float* __restrict__ dst, int drs, float scale)
{
    __shared__ float At[16][64];   // 4 KB
    __shared__ float Bt[64][32];   // 8 KB
    const int rt = blockIdx.x, ct = blockIdx.y, t = threadIdx.x;
    const int sk = ((ct * 32) >> 6) * scm;
    const int c  = t & 31;
    const int rg = t >> 5;             // 8 groups x 2 rows

    const int ar0 = t >> 4,          ak0 = t & 15;          // 1 float4 A
    const int bk0 = t >> 3,          bc0 = (t & 7) * 4;     // 2 float4 B
    const int bk1 = (t + 256) >> 3,  bc1 = ((t + 256) & 7) * 4;

    float4 va0, vb0, vb1;
    auto LD = [&](int kb) {
        va0 = *(const float4*)&src[(size_t)(rt * 16 + ar0) * ars + sk + kb * 64 + ak0 * 4];
        vb0 = *(const float4*)&W[(size_t)(kb * 64 + bk0) * DMODEL + ct * 32 + bc0];
        vb1 = *(const float4*)&W[(size_t)(kb * 64 + bk1) * DMODEL + ct * 32 + bc1];
    };

    LD(0);
    float acc[2] = {0.f, 0.f};

    for (int kb = 0; kb < 12; ++kb) {
        if (kb) __syncthreads();
        *(float4*)&At[ar0][ak0 * 4] = va0;
        *(float4*)&Bt[bk0][bc0] = vb0;
        *(float4*)&Bt[bk1][bc1] = vb1;
        __syncthreads();
        if (kb < 11) LD(kb + 1);
        #pragma unroll
        for (int kq = 0; kq < 16; ++kq) {
            float b0 = Bt[kq * 4 + 0][c], b1 = Bt[kq * 4 + 1][c];
            float b2 = Bt[kq * 4 + 2][c], b3 = Bt[kq * 4 + 3][c];
            #pragma unroll
            for (int i = 0; i < 2; ++i) {
                float4 a = *(const float4*)&At[rg * 2 + i][kq * 4];
                acc[i] += a.x * b0 + a.y * b1 + a.z * b2 + a.w * b3;
            }
        }
    }
    const float bb = bias[ct * 32 + c];
    #pragma unroll
    for (int i = 0; i < 2; ++i)
        dst[(size_t)(rt * 16 + rg * 2 + i) * drs + ct * 32 + c] = (acc[i] + bb) * scale;
}

// ---------------------------------------------------------------------------
// u[r, h, m] = sum_d Qp[r, h*64+d] * Wk[m, h*64+d];  cvec[r,h] = sum_d bk[h*64+d]*Qp[r,h*64+d]
// grid = (16, 12, 12), 256 threads
// ---------------------------------------------------------------------------
__global__ __launch_bounds__(256) void u_kernel(
    const float* __restrict__ qp, const float* __restrict__ Wk, const float* __restrict__ bk,
    float* __restrict__ u, float* __restrict__ cvec)
{
    __shared__ float Qt[32][64];    // 8 KB
    __shared__ float Bt[64][65];    // 16.25 KB (pad -> conflict-free b32 row reads)
    const int rt = blockIdx.x, mt = blockIdx.y, h = blockIdx.z, t = threadIdx.x;

    #pragma unroll
    for (int kk = 0; kk < 2; ++kk) {
        int i4 = t + kk * 256;
        int r = i4 >> 4, dq = i4 & 15;
        *(float4*)&Qt[r][dq * 4] =
            *(const float4*)&qp[(size_t)(rt * 32 + r) * DMODEL + h * 64 + dq * 4];
    }
    #pragma unroll
    for (int kk = 0; kk < 4; ++kk) {
        int i4 = t + kk * 256;
        int m = i4 >> 4, dq = i4 & 15;
        float4 v = *(const float4*)&Wk[(size_t)(mt * 64 + m) * DMODEL + h * 64 + dq * 4];
        Bt[m][dq * 4 + 0] = v.x; Bt[m][dq * 4 + 1] = v.y;
        Bt[m][dq * 4 + 2] = v.z; Bt[m][dq * 4 + 3] = v.w;
    }
    __syncthreads();

    const int c = t & 63, rg = t >> 6;
    float acc[8] = {0.f,0.f,0.f,0.f,0.f,0.f,0.f,0.f};
    #pragma unroll
    for (int dq = 0; dq < 16; ++dq) {
        float b0 = Bt[c][dq * 4 + 0], b1 = Bt[c][dq * 4 + 1];
        float b2 = Bt[c][dq * 4 + 2], b3 = Bt[c][dq * 4 + 3];
        #pragma unroll
        for (int i = 0; i < 8; ++i) {
            float4 a = *(const float4*)&Qt[rg * 8 + i][dq * 4];
            acc[i] += a.x * b0 + a.y * b1 + a.z * b2 + a.w * b3;
        }
    }
    #pragma unroll
    for (int i = 0; i < 8; ++i)
        u[(size_t)(rt * 32 + rg * 8 + i) * BIW + h * DMODEL + mt * 64 + c] = acc[i];

    if (mt == 0 && t < 32) {
        float s = 0.f;
        for (int d = 0; d < 64; ++d) s += bk[h * 64 + d] * Qt[t][d];
        cvec[(rt * 32 + t) * NHEADS + h] = s;
    }
}

// ---------------------------------------------------------------------------
// Core: per (b,i) block, 512 threads (8 waves).
// launch_bounds(512,2): >=128-VGPR cap -> NO scratch spill (R2-R4 had 64-VGPR
// cap and ~180 MB of spill traffic per dispatch).
// Phase 1: coalesced key stream (m across lanes), depth-1 prefetch, u in LDS,
// 30-shfl split-tree. Softmax per head per wave.
// Phase 3: j-split halves (value read once), partial-w reduce via u_sh.
// ---------------------------------------------------------------------------
__global__ __launch_bounds__(512, 2) void attn_core(
    const float* __restrict__ key, const float* __restrict__ value, const float* __restrict__ mask,
    const float* __restrict__ u, const float* __restrict__ cvec, float* __restrict__ w)
{
    __shared__ float u_sh[NHEADS * DMODEL];   // 36 KB (u in phase 1; w-partials in phase 3)
    __shared__ float sc[NHEADS][66];          // scores -> attn in place

    const int bi   = blockIdx.x;
    const int t    = threadIdx.x;
    const int lane = t & 63;
    const int wv   = t >> 6;                  // wave 0..7
    const size_t kvb = (size_t)bi * 64 * DMODEL;

    // stage u[bi] (36 KB), coalesced
    #pragma unroll
    for (int kk = 0; kk < 5; ++kk) {
        int idx = (t + kk * 512) * 4;
        if (idx < NHEADS * DMODEL)
            *(float4*)&u_sh[idx] = *(const float4*)&u[(size_t)bi * BIW + idx];
    }
    __syncthreads();

    // ---- phase 1: wave wv owns rows j = wv*8 .. wv*8+7, 4 rows per sub-iter
    #pragma unroll
    for (int rb = 0; rb < 2; ++rb) {
        const int j0 = wv * 8 + rb * 4;
        float a[NHEADS][4];
        #pragma unroll
        for (int h = 0; h < NHEADS; ++h)
            #pragma unroll
            for (int r = 0; r < 4; ++r) a[h][r] = 0.f;

        float4 kc[4], kn[4];
        #pragma unroll
        for (int r = 0; r < 4; ++r)
            kc[r] = *(const float4*)&key[kvb + (size_t)(j0 + r) * DMODEL + lane * 4];

        #pragma unroll
        for (int cch = 0; cch < 3; ++cch) {
            if (cch < 2) {
                #pragma unroll
                for (int r = 0; r < 4; ++r)
                    kn[r] = *(const float4*)&key[kvb + (size_t)(j0 + r) * DMODEL + (cch + 1) * 256 + lane * 4];
            }
            #pragma unroll
            for (int h = 0; h < NHEADS; ++h) {
                float4 u4 = *(const float4*)&u_sh[h * DMODEL + cch * 256 + lane * 4];
                #pragma unroll
                for (int r = 0; r < 4; ++r)
                    a[h][r] += kc[r].x * u4.x + kc[r].y * u4.y + kc[r].z * u4.z + kc[r].w * u4.w;
            }
            #pragma unroll
            for (int r = 0; r < 4; ++r) kc[r] = kn[r];
        }

        // split-tree reduce: 12 heads over 64 lanes -> 30 shfl per row
        #pragma unroll
        for (int r = 0; r < 4; ++r) {
            float s6[6];
            #pragma unroll
            for (int i = 0; i < 6; ++i) {
                float lo = a[i][r], hi = a[i + 6][r];
                float tl = __shfl_xor(lo, 32), th = __shfl_xor(hi, 32);
                s6[i] = (lane < 32) ? lo + tl : hi + th;
            }
            float s3[3];
            #pragma unroll
            for (int i = 0; i < 3; ++i) {
                float lo = s6[i], hi = s6[i + 3];
                float tl = __shfl_xor(lo, 16), th = __shfl_xor(hi, 16);
                s3[i] = ((lane & 16) == 0) ? lo + tl : hi + th;
            }
            #pragma unroll
            for (int o = 8; o >= 1; o >>= 1)
                #pragma unroll
                for (int i = 0; i < 3; ++i) s3[i] += __shfl_xor(s3[i], o);
            if ((lane & 15) == 0) {
                const int g = lane >> 4;
                #pragma unroll
                for (int i = 0; i < 3; ++i) sc[g * 3 + i][j0 + r] = s3[i];
            }
        }
    }
    __syncthreads();

    // ---- softmax: wave wv -> head wv; waves 0..3 also head 8+wv
    {
        const float mk = mask[bi * 64 + lane];
        #pragma unroll
        for (int hh = 0; hh < 2; ++hh) {
            const int h = wv + hh * 8;
            if (h < NHEADS) {
                float s = (sc[h][lane] + cvec[bi * NHEADS + h]) * mk;
                float mx = s;
                #pragma unroll
                for (int o = 1; o < 64; o <<= 1) mx = fmaxf(mx, __shfl_xor(mx, o));
                float e = __expf(s - mx);
                float sm = e;
                #pragma unroll
                for (int o = 1; o < 64; o <<= 1) sm += __shfl_xor(sm, o);
                sc[h][lane] = e / sm;
            }
        }
    }
    __syncthreads();

    // ---- phase 3: j-split halves. half hb: j in [hb*32, hb*32+32), ALL 12 heads,
    //      m = mo + {0,256,512}. value read exactly once per block.
    {
        const int hb = t >> 8, mo = t & 255;
        const int jbeg = hb * 32;
        float a3[NHEADS][3];
        #pragma unroll
        for (int h = 0; h < NHEADS; ++h) { a3[h][0] = 0.f; a3[h][1] = 0.f; a3[h][2] = 0.f; }
        const float* vb = value + kvb + mo;
        #pragma unroll 4
        for (int jj = 0; jj < 32; ++jj) {
            const int j = jbeg + jj;
            float v0 = vb[(size_t)j * DMODEL];
            float v1 = vb[(size_t)j * DMODEL + 256];
            float v2 = vb[(size_t)j * DMODEL + 512];
            #pragma unroll
            for (int h = 0; h < NHEADS; ++h) {
                float av = sc[h][j];
                a3[h][0] += av * v0;
                a3[h][1] += av * v1;
                a3[h][2] += av * v2;
            }
        }
        // reduce the two j-halves through u_sh (free after phase 1)
        if (hb == 0) {
            #pragma unroll
            for (int h = 0; h < NHEADS; ++h)
                #pragma unroll
                for (int mm = 0; mm < 3; ++mm)
                    u_sh[h * DMODEL + mo + mm * 256] = a3[h][mm];
        }
        __syncthreads();
        if (hb == 1) {
            #pragma unroll
            for (int h = 0; h < NHEADS; ++h)
                #pragma unroll
                for (int mm = 0; mm < 3; ++mm)
                    w[(size_t)bi * BIW + h * DMODEL + mo + mm * 256] =
                        a3[h][mm] + u_sh[h * DMODEL + mo + mm * 256];
        }
    }
}

// ---------------------------------------------------------------------------
extern "C" void kernel_launch(void* const* d_in, const int* in_sizes, int n_in,
                              void* d_out, int out_size, void* d_ws, size_t ws_size,
                              hipStream_t stream) {
    const float* key   = (const float*)d_in[0];
    const float* value = (const float*)d_in[1];
    const float* query = (const float*)d_in[2];
    const float* mask  = (const float*)d_in[3];
    const float* Wk    = (const float*)d_in[4];
    const float* bk    = (const float*)d_in[5];
    const float* Wv    = (const float*)d_in[6];
    const float* bv    = (const float*)d_in[7];
    const float* Wq    = (const float*)d_in[8];
    const float* bq    = (const float*)d_in[9];
    const float* Wo    = (const float*)d_in[10];
    const float* bo    = (const float*)d_in[11];
    float* out = (float*)d_out;

    float* wsf    = (float*)d_ws;
    float* qp_ctx = wsf;                                // 512*768 (Qp, later ctx)
    float* u_w    = wsf + (size_t)RTOT * DMODEL;        // 512*9216 (u, later w)
    float* cvec   = u_w + (size_t)RTOT * BIW;           // 512*12

    // 1. Qp = (query @ Wq + bq) / 8
    linear16<<<dim3(32, 24), 256, 0, stream>>>(query, DMODEL, 0, Wq, bq, qp_ctx, DMODEL, 0.125f);
    // 2. u[r,h,m], cvec[r,h]
    u_kernel<<<dim3(16, 12, 12), 256, 0, stream>>>(qp_ctx, Wk, bk, u_w, cvec);
    // 3. scores/softmax/w  (w overwrites u region; u staged to LDS before w writes)
    attn_core<<<512, 512, 0, stream>>>(key, value, mask, u_w, cvec, u_w);
    // 4. ctx[r, h*64+cc] = w[r,h,:] @ Wv[:, h*64+cc] + bv
    linear16<<<dim3(32, 24), 256, 0, stream>>>(u_w, BIW, DMODEL, Wv, bv, qp_ctx, DMODEL, 1.0f);
    // 5. out = ctx @ Wo + bo
    linear16<<<dim3(32, 24), 256, 0, stream>>>(qp_ctx, DMODEL, 0, Wo, bo, out, DMODEL, 1.0f);
}